// Round 3
// baseline (414.932 us; speedup 1.0000x reference)
//
#include <hip/hip_runtime.h>
#include <math.h>

#define Dm   1536
#define NHd  12
#define HDm  128
#define Ltok 4096
#define S1c  22
#define S2c  21
#define MFIX 5.0f      // fixed softmax max: p = exp(s - MFIX), fp16-safe
#define LOG2E 1.4426950408889634f

typedef __attribute__((ext_vector_type(8))) _Float16 f16x8;
typedef __attribute__((ext_vector_type(4))) float f32x4;
typedef __attribute__((ext_vector_type(16))) float f32x16;

static __device__ __forceinline__ f32x4 MFMA16(f16x8 a, f16x8 b, f32x4 c) {
  return __builtin_amdgcn_mfma_f32_16x16x32_f16(a, b, c, 0, 0, 0);
}
static __device__ __forceinline__ f32x16 MFMA32(f16x8 a, f16x8 b, f32x16 c) {
  return __builtin_amdgcn_mfma_f32_32x32x16_f16(a, b, c, 0, 0, 0);
}

static __device__ __forceinline__ unsigned int pack_f16(float a, float b) {
  union { _Float16 h[2]; unsigned int u; } x;
  x.h[0] = (_Float16)a; x.h[1] = (_Float16)b;
  return x.u;
}

// async global->LDS, 16B per lane; LDS dest = wave-uniform base + lane*16
static __device__ __forceinline__ void gload_lds16(const void* g, void* l) {
  __builtin_amdgcn_global_load_lds(
      (const __attribute__((address_space(1))) unsigned int*)g,
      (__attribute__((address_space(3))) unsigned int*)l, 16, 0, 0);
}

// ---------------------------------------------------------------------------
// fp32 -> fp16 convert, flat (n float4 slots)
// ---------------------------------------------------------------------------
__global__ __launch_bounds__(256) void cvt_f16(
    const float* __restrict__ src, unsigned short* __restrict__ dst, int nslots)
{
  int i = blockIdx.x * 256 + threadIdx.x;
  if (i >= nslots) return;
  float4 v = *(const float4*)&src[(size_t)i * 4];
  uint2 p;
  p.x = pack_f16(v.x, v.y);
  p.y = pack_f16(v.z, v.w);
  *(uint2*)&dst[(size_t)i * 4] = p;
}

// convert 4 weight matrices in one dispatch (blockIdx.y selects)
__global__ __launch_bounds__(256) void cvt_w4_f16(
    const float* __restrict__ w0, const float* __restrict__ w1,
    const float* __restrict__ w2, const float* __restrict__ w3,
    unsigned short* __restrict__ dst)
{
  const int which = blockIdx.y;
  const float* src = (which == 0) ? w0 : (which == 1) ? w1 : (which == 2) ? w2 : w3;
  unsigned short* d = dst + (size_t)which * Dm * Dm;
  int i = blockIdx.x * 256 + threadIdx.x;
  float4 v = *(const float4*)&src[(size_t)i * 4];
  uint2 p;
  p.x = pack_f16(v.x, v.y);
  p.y = pack_f16(v.z, v.w);
  *(uint2*)&d[(size_t)i * 4] = p;
}

// ---------------------------------------------------------------------------
// Fused QKV fp16 NT GEMM: A[4096][1536]h @ W[4608][1536]h^T.
// 128x128 tile, 4 waves (2x2 of 64x64), BK=32, double-buffered LDS with
// COUNTED vmcnt + raw s_barrier: tile t+1's global_load_lds stay in flight
// across the barrier while tile t's MFMAs run (T3+T4).
// ---------------------------------------------------------------------------
__global__ __launch_bounds__(256) void gemm_qkv_f16(
    const unsigned short* __restrict__ Ag, const unsigned short* __restrict__ Wg,
    const float* __restrict__ bq, const float* __restrict__ bk,
    const float* __restrict__ bv,
    float* __restrict__ qb, float* __restrict__ kb,
    unsigned short* __restrict__ vT)
{
  __shared__ __align__(16) unsigned short As[2][128][32], Bs[2][128][32];  // 32 KB
  const int tid = threadIdx.x;
  const int w = tid >> 6, lane = tid & 63;
  const int nx = lane & 15, g = lane >> 4;
  const int m0 = blockIdx.y * 128, n0 = blockIdx.x * 128;   // n0 in [0,4608)
  const int wr = w >> 1, wc = w & 1;
  const int which = (n0 >= 2 * Dm) ? 2 : ((n0 >= Dm) ? 1 : 0);
  const int n0loc = n0 - which * Dm;

  // staging: waves 0-1 -> A rows w*64.., waves 2-3 -> B rows (w-2)*64..
  const int srow = lane >> 2, scol = (lane & 3) * 8;
  const unsigned short* gp;
  char* lbase0;
  if (w < 2) {
    gp = Ag + (size_t)(m0 + w * 64 + srow) * Dm + scol;
    lbase0 = (char*)&As[0][0][0] + w * 4096;
  } else {
    gp = Wg + (size_t)(n0 + (w - 2) * 64 + srow) * Dm + scol;
    lbase0 = (char*)&Bs[0][0][0] + (w - 2) * 4096;
  }

  f32x4 acc[4][4];
#pragma unroll
  for (int i = 0; i < 4; i++)
#pragma unroll
    for (int j = 0; j < 4; j++) acc[i][j] = (f32x4){0.f, 0.f, 0.f, 0.f};

  // prologue: stage tile 0 into buffer 0 (4 loads in flight)
#pragma unroll
  for (int c = 0; c < 4; ++c)
    gload_lds16(gp + (size_t)c * 16 * Dm, lbase0 + c * 1024);
  gp += 32;

  const int NK = Dm / 32;
  for (int it = 0; it < NK; ++it) {
    const int cur = it & 1;
    if (it + 1 < NK) {          // issue t+1 into the other buffer (stays in flight)
      char* lb = lbase0 + (cur ^ 1) * 8192;
#pragma unroll
      for (int c = 0; c < 4; ++c)
        gload_lds16(gp + (size_t)c * 16 * Dm, lb + c * 1024);
      gp += 32;
      asm volatile("s_waitcnt vmcnt(4)" ::: "memory");   // drain tile t only
    } else {
      asm volatile("s_waitcnt vmcnt(0)" ::: "memory");
    }
    __builtin_amdgcn_s_barrier();   // buffer cur fully written, all waves
    f16x8 ah[4], bh[4];
#pragma unroll
    for (int i = 0; i < 4; ++i) {
      ah[i] = *(const f16x8*)&As[cur][wr * 64 + i * 16 + nx][g * 8];
      bh[i] = *(const f16x8*)&Bs[cur][wc * 64 + i * 16 + nx][g * 8];
    }
#pragma unroll
    for (int i = 0; i < 4; ++i)
#pragma unroll
      for (int j = 0; j < 4; ++j)
        acc[i][j] = MFMA16(ah[i], bh[j], acc[i][j]);
    __builtin_amdgcn_s_barrier();   // reads of cur done -> next iter may overwrite
  }

  if (which < 2) {      // q or k tile: fp32 row-major out
    float* Cout = which ? kb : qb;
    const float* bias = which ? bk : bq;
#pragma unroll
    for (int j = 0; j < 4; ++j) {
      const int col = n0loc + wc * 64 + j * 16 + nx;
      const float bz = bias[col];
#pragma unroll
      for (int i = 0; i < 4; ++i) {
        const int row0 = m0 + wr * 64 + i * 16 + g * 4;
#pragma unroll
        for (int r = 0; r < 4; ++r)
          Cout[(size_t)(row0 + r) * Dm + col] = acc[i][j][r] + bz;
      }
    }
  } else {              // v tile: fp16 V^T [col][row] directly
#pragma unroll
    for (int j = 0; j < 4; ++j) {
      const int col = n0loc + wc * 64 + j * 16 + nx;  // head*128+ch
      const float bz = bv[col];
#pragma unroll
      for (int i = 0; i < 4; ++i) {
        const int row0 = m0 + wr * 64 + i * 16 + g * 4;
        uint2 pk;
        pk.x = pack_f16(acc[i][j][0] + bz, acc[i][j][1] + bz);
        pk.y = pack_f16(acc[i][j][2] + bz, acc[i][j][3] + bz);
        *(uint2*)&vT[(size_t)col * Ltok + row0] = pk;
      }
    }
  }
}

// ---------------------------------------------------------------------------
// fp16 NT GEMM (out-projection): C[4096][1536]f32 = A·W^T + bias
// Same counted-vmcnt double-buffered structure.
// ---------------------------------------------------------------------------
__global__ __launch_bounds__(256) void gemm_nt_f16(
    const unsigned short* __restrict__ Ag, const unsigned short* __restrict__ Wg,
    const float* __restrict__ bias, float* __restrict__ Cout)
{
  __shared__ __align__(16) unsigned short As[2][128][32], Bs[2][128][32];
  const int tid = threadIdx.x;
  const int w = tid >> 6, lane = tid & 63;
  const int nx = lane & 15, g = lane >> 4;
  const int m0 = blockIdx.y * 128, n0 = blockIdx.x * 128;
  const int wr = w >> 1, wc = w & 1;

  const int srow = lane >> 2, scol = (lane & 3) * 8;
  const unsigned short* gp;
  char* lbase0;
  if (w < 2) {
    gp = Ag + (size_t)(m0 + w * 64 + srow) * Dm + scol;
    lbase0 = (char*)&As[0][0][0] + w * 4096;
  } else {
    gp = Wg + (size_t)(n0 + (w - 2) * 64 + srow) * Dm + scol;
    lbase0 = (char*)&Bs[0][0][0] + (w - 2) * 4096;
  }

  f32x4 acc[4][4];
#pragma unroll
  for (int i = 0; i < 4; i++)
#pragma unroll
    for (int j = 0; j < 4; j++) acc[i][j] = (f32x4){0.f, 0.f, 0.f, 0.f};

#pragma unroll
  for (int c = 0; c < 4; ++c)
    gload_lds16(gp + (size_t)c * 16 * Dm, lbase0 + c * 1024);
  gp += 32;

  const int NK = Dm / 32;
  for (int it = 0; it < NK; ++it) {
    const int cur = it & 1;
    if (it + 1 < NK) {
      char* lb = lbase0 + (cur ^ 1) * 8192;
#pragma unroll
      for (int c = 0; c < 4; ++c)
        gload_lds16(gp + (size_t)c * 16 * Dm, lb + c * 1024);
      gp += 32;
      asm volatile("s_waitcnt vmcnt(4)" ::: "memory");
    } else {
      asm volatile("s_waitcnt vmcnt(0)" ::: "memory");
    }
    __builtin_amdgcn_s_barrier();
    f16x8 ah[4], bh[4];
#pragma unroll
    for (int i = 0; i < 4; ++i) {
      ah[i] = *(const f16x8*)&As[cur][wr * 64 + i * 16 + nx][g * 8];
      bh[i] = *(const f16x8*)&Bs[cur][wc * 64 + i * 16 + nx][g * 8];
    }
#pragma unroll
    for (int i = 0; i < 4; ++i)
#pragma unroll
      for (int j = 0; j < 4; ++j)
        acc[i][j] = MFMA16(ah[i], bh[j], acc[i][j]);
    __builtin_amdgcn_s_barrier();
  }
#pragma unroll
  for (int j = 0; j < 4; ++j) {
    const int col = n0 + wc * 64 + j * 16 + nx;
    const float bz = bias[col];
#pragma unroll
    for (int i = 0; i < 4; ++i) {
      const int row0 = m0 + wr * 64 + i * 16 + g * 4;
#pragma unroll
      for (int r = 0; r < 4; ++r)
        Cout[(size_t)(row0 + r) * Dm + col] = acc[i][j][r] + bz;
    }
  }
}

// ---------------------------------------------------------------------------
// RMSNorm over full D + 3D rope; fp32 in -> fp16 rows in-place.
// Q pre-scaled by 1/sqrt(HD) * log2(e)  (softmax exp folded into exp2).
// ---------------------------------------------------------------------------
__global__ __launch_bounds__(256) void rmsnorm_rope_f16(
    float* __restrict__ q, float* __restrict__ k,
    const float* __restrict__ gq, const float* __restrict__ gk,
    const float* __restrict__ fcos, const float* __restrict__ fsin)
{
  const int l = blockIdx.x;
  const int tid = threadIdx.x;
  const int d0 = tid * 6;
  float qv[6], kv[6];
  float sq = 0.f, sk = 0.f;
  const float* qp = &q[(size_t)l * Dm + d0];
  const float* kp = &k[(size_t)l * Dm + d0];
#pragma unroll
  for (int i = 0; i < 6; i++) {
    qv[i] = qp[i]; sq += qv[i] * qv[i];
    kv[i] = kp[i]; sk += kv[i] * kv[i];
  }
#pragma unroll
  for (int s = 1; s < 64; s <<= 1) {
    sq += __shfl_xor(sq, s);
    sk += __shfl_xor(sk, s);
  }
  __shared__ float redq[4], redk[4];
  if ((tid & 63) == 0) { redq[tid >> 6] = sq; redk[tid >> 6] = sk; }
  __syncthreads();
  sq = redq[0] + redq[1] + redq[2] + redq[3];
  sk = redk[0] + redk[1] + redk[2] + redk[3];
  const float rq = rsqrtf(sq * (1.f / (float)Dm) + 1e-6f);
  const float rk = rsqrtf(sk * (1.f / (float)Dm) + 1e-6f);
  const float qscale = 0.08838834764831845f * LOG2E;   // 1/sqrt(128) * log2(e)
  const int f = l >> 10, h = (l >> 5) & 31, w = l & 31;
  unsigned short* qo = (unsigned short*)q + (size_t)l * Dm;
  unsigned short* ko = (unsigned short*)k + (size_t)l * Dm;
#pragma unroll
  for (int i = 0; i < 3; i++) {
    const int d = d0 + 2 * i;
    const int cc = (d & (HDm - 1)) >> 1;
    const int pos = (cc < S1c) ? f : ((cc < S1c + S2c) ? h : w);
    const float co = fcos[pos * 64 + cc];
    const float si = fsin[pos * 64 + cc];
    const float xr = qv[2 * i]     * rq * gq[d];
    const float xi = qv[2 * i + 1] * rq * gq[d + 1];
    *(unsigned int*)&qo[d] =
        pack_f16((xr * co - xi * si) * qscale, (xr * si + xi * co) * qscale);
    const float yr = kv[2 * i]     * rk * gk[d];
    const float yi = kv[2 * i + 1] * rk * gk[d + 1];
    *(unsigned int*)&ko[d] = pack_f16(yr * co - yi * si, yr * si + yi * co);
  }
}

// ---------------------------------------------------------------------------
// Flash attention, 32x32x16 MFMA, fixed-max softmax, split-KV x2.
// LDS diet: P never touches LDS. In the 32x32 S^T layout each lane's 16
// S-values belong to ONE q-row (col = lane&31), so the P -> PV-A-fragment
// fix-up is a pure low/high half-wave word exchange (permlane32_swap
// semantics, emulated with shfl_xor + selects):
//   swap(W[i], W[i+2]) for i in {0,1,4,5};  frags = (W0..W3), (W4..W7).
// Rowsum l = 16 in-lane adds + one shfl_xor(32).
// ---------------------------------------------------------------------------
__global__ __launch_bounds__(256, 3) void attn_f16(
    const unsigned short* __restrict__ qs, const unsigned short* __restrict__ ks,
    const unsigned short* __restrict__ vT,
    float* __restrict__ Op0, float* __restrict__ Op1,
    float* __restrict__ stats)
{
  __shared__ __align__(16) unsigned short Ks[2][32][136];
  __shared__ __align__(16) unsigned short Vs[2][128][40];

  const int tid = threadIdx.x;
  const int w = tid >> 6, lane = tid & 63;
  const int lx = lane & 31, hi = lane >> 5;
  const int head = blockIdx.y;
  const int half = blockIdx.z;
  const int qbase = blockIdx.x * 128 + w * 32;
  const int kvbase = half * (Ltok / 2);
  float* __restrict__ Op = half ? Op1 : Op0;

  const float NEGMFIX2 = -MFIX * LOG2E;   // -7.2134752

  // ---- Q fragments: B[n=q=lx][k = hi*8+j], 8 ch-chunks of 16 ----
  f16x8 qf[8];
  {
    const unsigned short* qp = &qs[(size_t)(qbase + lx) * Dm + head * HDm + hi * 8];
#pragma unroll
    for (int c = 0; c < 8; c++) qf[c] = *(const f16x8*)(qp + c * 16);
  }

  f32x16 oat[4];
#pragma unroll
  for (int nt = 0; nt < 4; nt++)
#pragma unroll
    for (int r = 0; r < 16; r++) oat[nt][r] = 0.f;
  float lrow = 0.f;

  const int krow = tid >> 3, kchb = (tid & 7) << 4;
  const int vrow = tid >> 1, vseg = (tid & 1) << 4;

  const unsigned short* kg = &ks[(size_t)(kvbase + krow) * Dm + head * HDm + kchb];
  const unsigned short* vg = &vT[((size_t)head * HDm + vrow) * Ltok + kvbase + vseg];

  // preload tile 0 into buffer 0
  {
    uint4 ka = *(const uint4*)kg, kb4 = *(const uint4*)(kg + 8);
    uint4 va = *(const uint4*)vg, vb4 = *(const uint4*)(vg + 8);
    *(uint4*)&Ks[0][krow][kchb]     = ka;
    *(uint4*)&Ks[0][krow][kchb + 8] = kb4;
    *(uint4*)&Vs[0][vrow][vseg]     = va;
    *(uint4*)&Vs[0][vrow][vseg + 8] = vb4;
  }
  __syncthreads();

  const int NIT = Ltok / 2 / 32;   // 64
  for (int t = 0; t < NIT; t++) {
    const int cur = t & 1, nxt = cur ^ 1;
    const bool pref = (t + 1 < NIT);
    uint4 ka, kb4, va, vb4;
    if (pref) {           // issue t+1 global loads early
      kg += 32 * Dm;
      vg += 32;
      ka  = *(const uint4*)kg;  kb4 = *(const uint4*)(kg + 8);
      va  = *(const uint4*)vg;  vb4 = *(const uint4*)(vg + 8);
    }

    // ---- S^T = K · Q^T, 32x32 (C-in = -MFIX*log2e) ----
    f32x16 sa;
#pragma unroll
    for (int r = 0; r < 16; r++) sa[r] = NEGMFIX2;
#pragma unroll
    for (int c = 0; c < 8; c++) {
      f16x8 kf = *(const f16x8*)&Ks[cur][lx][c * 16 + hi * 8];
      sa = MFMA32(kf, qf[c], sa);
    }

    // ---- p = exp2(sa); rowsum (all 16 values are q = lx) ----
    float p[16], ps = 0.f;
#pragma unroll
    for (int r = 0; r < 16; r++) {
      p[r] = __builtin_amdgcn_exp2f(sa[r]);
      ps += p[r];
    }
    lrow += ps + __shfl_xor(ps, 32);

    // ---- pack to f16 words; reg r pair -> kv = (r&3)+8*(r>>2)+4*hi ----
    unsigned int W0 = pack_f16(p[0],  p[1]),  W1 = pack_f16(p[2],  p[3]);
    unsigned int W2 = pack_f16(p[4],  p[5]),  W3 = pack_f16(p[6],  p[7]);
    unsigned int W4 = pack_f16(p[8],  p[9]),  W5 = pack_f16(p[10], p[11]);
    unsigned int W6 = pack_f16(p[12], p[13]), W7 = pack_f16(p[14], p[15]);

    // ---- permlane32_swap(Wa, Wb) emulation: one shfl_xor + selects ----
#define HALFSWAP(Wa, Wb)                                            \
    {                                                               \
      unsigned int x_ = hi ? (Wa) : (Wb);                           \
      unsigned int s_ = (unsigned int)__shfl_xor((int)x_, 32);      \
      unsigned int na_ = hi ? s_ : (Wa);                            \
      unsigned int nb_ = hi ? (Wb) : s_;                            \
      (Wa) = na_; (Wb) = nb_;                                       \
    }
    HALFSWAP(W0, W2); HALFSWAP(W1, W3);
    HALFSWAP(W4, W6); HALFSWAP(W5, W7);
#undef HALFSWAP

    union { unsigned int u[4]; f16x8 v; } pa0, pa1;
    pa0.u[0] = W0; pa0.u[1] = W1; pa0.u[2] = W2; pa0.u[3] = W3;  // kv chunk 0-15
    pa1.u[0] = W4; pa1.u[1] = W5; pa1.u[2] = W6; pa1.u[3] = W7;  // kv chunk 16-31

    // ---- O += P · V, 4 ch-tiles x 2 kv-chunks ----
#pragma unroll
    for (int nt = 0; nt < 4; nt++) {
      f16x8 v0 = *(const f16x8*)&Vs[cur][nt * 32 + lx][hi * 8];
      f16x8 v1 = *(const f16x8*)&Vs[cur][nt * 32 + lx][16 + hi * 8];
      oat[nt] = MFMA32(pa0.v, v0, oat[nt]);
      oat[nt] = MFMA32(pa1.v, v1, oat[nt]);
    }

    if (pref) {           // stage t+1 into the other buffer
      *(uint4*)&Ks[nxt][krow][kchb]     = ka;
      *(uint4*)&Ks[nxt][krow][kchb + 8] = kb4;
      *(uint4*)&Vs[nxt][vrow][vseg]     = va;
      *(uint4*)&Vs[nxt][vrow][vseg + 8] = vb4;
    }
    __syncthreads();
  }

  // ---- epilogue: raw partial O + l stats ----
#pragma unroll
  for (int nt = 0; nt < 4; nt++)
#pragma unroll
    for (int r = 0; r < 16; r++) {
      const int qo = (r & 3) + 8 * (r >> 2) + 4 * hi;
      Op[(size_t)(qbase + qo) * Dm + head * HDm + nt * 32 + lx] = oat[nt][r];
    }
  if (hi == 0)
    stats[((size_t)half * Ltok + qbase + lx) * NHd + head] = lrow;
}

// ---------------------------------------------------------------------------
// Combine the two KV-half partials (same fixed M -> exact merge); emit fp16
// rows for the out-projection.
// ---------------------------------------------------------------------------
__global__ __launch_bounds__(384) void combine_f16(
    const float* __restrict__ Op0, const float* __restrict__ Op1,
    const float* __restrict__ stats, unsigned short* __restrict__ oh)
{
  const int row = blockIdx.x;
  const int c4 = threadIdx.x * 4;
  const int head = c4 >> 7;
  const float l0 = stats[(size_t)row * NHd + head];
  const float l1 = stats[((size_t)Ltok + row) * NHd + head];
  const float rl = 1.f / (l0 + l1);
  float4 o0 = *(const float4*)&Op0[(size_t)row * Dm + c4];
  float4 o1 = *(const float4*)&Op1[(size_t)row * Dm + c4];
  uint2 p;
  p.x = pack_f16((o0.x + o1.x) * rl, (o0.y + o1.y) * rl);
  p.y = pack_f16((o0.z + o1.z) * rl, (o0.w + o1.w) * rl);
  *(uint2*)&oh[(size_t)row * Dm + c4] = p;
}

// ---------------------------------------------------------------------------
extern "C" void kernel_launch(void* const* d_in, const int* in_sizes, int n_in,
                              void* d_out, int out_size, void* d_ws, size_t ws_size,
                              hipStream_t stream)
{
  const float* x    = (const float*)d_in[0];
  const float* wq   = (const float*)d_in[1];
  const float* wk   = (const float*)d_in[2];
  const float* wv   = (const float*)d_in[3];
  const float* wo   = (const float*)d_in[4];
  const float* bq   = (const float*)d_in[5];
  const float* bk   = (const float*)d_in[6];
  const float* bv   = (const float*)d_in[7];
  const float* bo   = (const float*)d_in[8];
  const float* gq   = (const float*)d_in[9];
  const float* gk   = (const float*)d_in[10];
  const float* fcos = (const float*)d_in[11];
  const float* fsin = (const float*)d_in[12];
  float* out = (float*)d_out;

  const size_t LD = (size_t)Ltok * Dm;       // 6.29 M elems
  const size_t WH = (size_t)Dm * Dm;         // 2.36 M shorts per fp16 weight
  float* base = (float*)d_ws;
  // Lifetime-checked layout (float offsets, total 5.27*LD = 132.6 MB):
  //  [0,   LD)      qb fp32 -> fp16 rows in place; after attn: oh fp16 rows
  //  [LD, 2LD)      kb fp32 -> fp16 rows in place
  //  [2LD, 2.5LD)   vT fp16 V^T (written by gemm_qkv, read by attn)
  //  [2.5LD, 3.5LD) Op0 fp32 (attn out); xh fp16 aliases [2.5LD,3LD) before
  //  [3.5LD, 4.5LD) Op1 fp32
  //  [4.5LD, 5.25LD) wqh|wkh|wvh|woh fp16 weights
  //  [5.25LD, ...)  stats (2*4096*12 fp32)
  float* qb = base;
  float* kb = base + LD;
  unsigned short* vT  = (unsigned short*)(base + 2 * LD);
  unsigned short* xh  = (unsigned short*)(base + 2 * LD + LD / 2);
  float* Op0 = base + 2 * LD + LD / 2;
  float* Op1 = Op0 + LD;
  unsigned short* wqh = (unsigned short*)(Op1 + LD);
  unsigned short* woh = wqh + 3 * WH;
  unsigned short* oh  = (unsigned short*)base;   // over dead q fp16 rows
  float* stats = (float*)(wqh + 4 * WH);

  const int xslots = (int)(LD / 4);          // 1572864
  const int w4     = (int)(WH / 4);          // 589824 = 2304*256
  dim3 gqkv(3 * Dm / 128, Ltok / 128);       // (36, 32)
  dim3 gout(Dm / 128, Ltok / 128);           // (12, 32)

  cvt_f16<<<(xslots + 255) / 256, 256, 0, stream>>>(x, xh, xslots);
  cvt_w4_f16<<<dim3(w4 / 256, 4), 256, 0, stream>>>(wq, wk, wv, wo, wqh);

  gemm_qkv_f16<<<gqkv, 256, 0, stream>>>(xh, wqh, bq, bk, bv, qb, kb, vT);
  rmsnorm_rope_f16<<<Ltok, 256, 0, stream>>>(qb, kb, gq, gk, fcos, fsin);
  attn_f16<<<dim3(Ltok / 128, NHd, 2), 256, 0, stream>>>(
      (const unsigned short*)qb, (const unsigned short*)kb, vT, Op0, Op1, stats);
  combine_f16<<<Ltok, 384, 0, stream>>>(Op0, Op1, stats, oh);
  gemm_nt_f16<<<gout, 256, 0, stream>>>(oh, woh, bo, out);
}

// Round 7
// 394.574 us; speedup vs baseline: 1.0516x; 1.0516x over previous
//
#include <hip/hip_runtime.h>
#include <math.h>

#define Dm   1536
#define NHd  12
#define HDm  128
#define Ltok 4096
#define S1c  22
#define S2c  21
#define MFIX 5.0f      // fixed softmax max: p = exp(s - MFIX), fp16-safe
#define LOG2E 1.4426950408889634f

typedef __attribute__((ext_vector_type(8))) _Float16 f16x8;
typedef __attribute__((ext_vector_type(4))) float f32x4;

static __device__ __forceinline__ f32x4 MFMA16(f16x8 a, f16x8 b, f32x4 c) {
  return __builtin_amdgcn_mfma_f32_16x16x32_f16(a, b, c, 0, 0, 0);
}

static __device__ __forceinline__ unsigned int pack_f16(float a, float b) {
  union { _Float16 h[2]; unsigned int u; } x;
  x.h[0] = (_Float16)a; x.h[1] = (_Float16)b;
  return x.u;
}

// async global->LDS, 16B per lane; LDS dest = wave-uniform base + lane*16
static __device__ __forceinline__ void gload_lds16(const void* g, void* l) {
  __builtin_amdgcn_global_load_lds(
      (const __attribute__((address_space(1))) unsigned int*)g,
      (__attribute__((address_space(3))) unsigned int*)l, 16, 0, 0);
}

// ---------------------------------------------------------------------------
// fp32 -> fp16 convert, flat (n float4 slots)
// ---------------------------------------------------------------------------
__global__ __launch_bounds__(256) void cvt_f16(
    const float* __restrict__ src, unsigned short* __restrict__ dst, int nslots)
{
  int i = blockIdx.x * 256 + threadIdx.x;
  if (i >= nslots) return;
  float4 v = *(const float4*)&src[(size_t)i * 4];
  uint2 p;
  p.x = pack_f16(v.x, v.y);
  p.y = pack_f16(v.z, v.w);
  *(uint2*)&dst[(size_t)i * 4] = p;
}

// convert 4 weight matrices in one dispatch (blockIdx.y selects)
__global__ __launch_bounds__(256) void cvt_w4_f16(
    const float* __restrict__ w0, const float* __restrict__ w1,
    const float* __restrict__ w2, const float* __restrict__ w3,
    unsigned short* __restrict__ dst)
{
  const int which = blockIdx.y;
  const float* src = (which == 0) ? w0 : (which == 1) ? w1 : (which == 2) ? w2 : w3;
  unsigned short* d = dst + (size_t)which * Dm * Dm;
  int i = blockIdx.x * 256 + threadIdx.x;
  float4 v = *(const float4*)&src[(size_t)i * 4];
  uint2 p;
  p.x = pack_f16(v.x, v.y);
  p.y = pack_f16(v.z, v.w);
  *(uint2*)&d[(size_t)i * 4] = p;
}

// ---------------------------------------------------------------------------
// Fused QKV fp16 NT GEMM: A[4096][1536]h @ W[4608][1536]h^T.
// 128x128 tile, 4 waves (2x2 of 64x64), BK=32, double-buffered LDS with
// COUNTED vmcnt + raw s_barrier (tile t+1 loads in flight under tile t MFMAs).
// ---------------------------------------------------------------------------
__global__ __launch_bounds__(256) void gemm_qkv_f16(
    const unsigned short* __restrict__ Ag, const unsigned short* __restrict__ Wg,
    const float* __restrict__ bq, const float* __restrict__ bk,
    const float* __restrict__ bv,
    float* __restrict__ qb, float* __restrict__ kb,
    unsigned short* __restrict__ vT)
{
  __shared__ __align__(16) unsigned short As[2][128][32], Bs[2][128][32];  // 32 KB
  const int tid = threadIdx.x;
  const int w = tid >> 6, lane = tid & 63;
  const int nx = lane & 15, g = lane >> 4;
  const int m0 = blockIdx.y * 128, n0 = blockIdx.x * 128;   // n0 in [0,4608)
  const int wr = w >> 1, wc = w & 1;
  const int which = (n0 >= 2 * Dm) ? 2 : ((n0 >= Dm) ? 1 : 0);
  const int n0loc = n0 - which * Dm;

  // staging: waves 0-1 -> A rows w*64.., waves 2-3 -> B rows (w-2)*64..
  const int srow = lane >> 2, scol = (lane & 3) * 8;
  const unsigned short* gp;
  char* lbase0;
  if (w < 2) {
    gp = Ag + (size_t)(m0 + w * 64 + srow) * Dm + scol;
    lbase0 = (char*)&As[0][0][0] + w * 4096;
  } else {
    gp = Wg + (size_t)(n0 + (w - 2) * 64 + srow) * Dm + scol;
    lbase0 = (char*)&Bs[0][0][0] + (w - 2) * 4096;
  }

  f32x4 acc[4][4];
#pragma unroll
  for (int i = 0; i < 4; i++)
#pragma unroll
    for (int j = 0; j < 4; j++) acc[i][j] = (f32x4){0.f, 0.f, 0.f, 0.f};

  // prologue: stage tile 0 into buffer 0 (4 loads in flight)
#pragma unroll
  for (int c = 0; c < 4; ++c)
    gload_lds16(gp + (size_t)c * 16 * Dm, lbase0 + c * 1024);
  gp += 32;

  const int NK = Dm / 32;
  for (int it = 0; it < NK; ++it) {
    const int cur = it & 1;
    if (it + 1 < NK) {          // issue t+1 into the other buffer (stays in flight)
      char* lb = lbase0 + (cur ^ 1) * 8192;
#pragma unroll
      for (int c = 0; c < 4; ++c)
        gload_lds16(gp + (size_t)c * 16 * Dm, lb + c * 1024);
      gp += 32;
      asm volatile("s_waitcnt vmcnt(4)" ::: "memory");   // drain tile t only
    } else {
      asm volatile("s_waitcnt vmcnt(0)" ::: "memory");
    }
    __builtin_amdgcn_s_barrier();   // buffer cur fully written, all waves
    f16x8 ah[4], bh[4];
#pragma unroll
    for (int i = 0; i < 4; ++i) {
      ah[i] = *(const f16x8*)&As[cur][wr * 64 + i * 16 + nx][g * 8];
      bh[i] = *(const f16x8*)&Bs[cur][wc * 64 + i * 16 + nx][g * 8];
    }
#pragma unroll
    for (int i = 0; i < 4; ++i)
#pragma unroll
      for (int j = 0; j < 4; ++j)
        acc[i][j] = MFMA16(ah[i], bh[j], acc[i][j]);
    __builtin_amdgcn_s_barrier();   // reads of cur done -> next iter may overwrite
  }

  if (which < 2) {      // q or k tile: fp32 row-major out
    float* Cout = which ? kb : qb;
    const float* bias = which ? bk : bq;
#pragma unroll
    for (int j = 0; j < 4; ++j) {
      const int col = n0loc + wc * 64 + j * 16 + nx;
      const float bz = bias[col];
#pragma unroll
      for (int i = 0; i < 4; ++i) {
        const int row0 = m0 + wr * 64 + i * 16 + g * 4;
#pragma unroll
        for (int r = 0; r < 4; ++r)
          Cout[(size_t)(row0 + r) * Dm + col] = acc[i][j][r] + bz;
      }
    }
  } else {              // v tile: fp16 V^T [col][row] directly
#pragma unroll
    for (int j = 0; j < 4; ++j) {
      const int col = n0loc + wc * 64 + j * 16 + nx;  // head*128+ch
      const float bz = bv[col];
#pragma unroll
      for (int i = 0; i < 4; ++i) {
        const int row0 = m0 + wr * 64 + i * 16 + g * 4;
        uint2 pk;
        pk.x = pack_f16(acc[i][j][0] + bz, acc[i][j][1] + bz);
        pk.y = pack_f16(acc[i][j][2] + bz, acc[i][j][3] + bz);
        *(uint2*)&vT[(size_t)col * Ltok + row0] = pk;
      }
    }
  }
}

// ---------------------------------------------------------------------------
// fp16 NT GEMM (out-projection): C[4096][1536]f32 = A·W^T + bias
// Same counted-vmcnt double-buffered structure.
// ---------------------------------------------------------------------------
__global__ __launch_bounds__(256) void gemm_nt_f16(
    const unsigned short* __restrict__ Ag, const unsigned short* __restrict__ Wg,
    const float* __restrict__ bias, float* __restrict__ Cout)
{
  __shared__ __align__(16) unsigned short As[2][128][32], Bs[2][128][32];
  const int tid = threadIdx.x;
  const int w = tid >> 6, lane = tid & 63;
  const int nx = lane & 15, g = lane >> 4;
  const int m0 = blockIdx.y * 128, n0 = blockIdx.x * 128;
  const int wr = w >> 1, wc = w & 1;

  const int srow = lane >> 2, scol = (lane & 3) * 8;
  const unsigned short* gp;
  char* lbase0;
  if (w < 2) {
    gp = Ag + (size_t)(m0 + w * 64 + srow) * Dm + scol;
    lbase0 = (char*)&As[0][0][0] + w * 4096;
  } else {
    gp = Wg + (size_t)(n0 + (w - 2) * 64 + srow) * Dm + scol;
    lbase0 = (char*)&Bs[0][0][0] + (w - 2) * 4096;
  }

  f32x4 acc[4][4];
#pragma unroll
  for (int i = 0; i < 4; i++)
#pragma unroll
    for (int j = 0; j < 4; j++) acc[i][j] = (f32x4){0.f, 0.f, 0.f, 0.f};

#pragma unroll
  for (int c = 0; c < 4; ++c)
    gload_lds16(gp + (size_t)c * 16 * Dm, lbase0 + c * 1024);
  gp += 32;

  const int NK = Dm / 32;
  for (int it = 0; it < NK; ++it) {
    const int cur = it & 1;
    if (it + 1 < NK) {
      char* lb = lbase0 + (cur ^ 1) * 8192;
#pragma unroll
      for (int c = 0; c < 4; ++c)
        gload_lds16(gp + (size_t)c * 16 * Dm, lb + c * 1024);
      gp += 32;
      asm volatile("s_waitcnt vmcnt(4)" ::: "memory");
    } else {
      asm volatile("s_waitcnt vmcnt(0)" ::: "memory");
    }
    __builtin_amdgcn_s_barrier();
    f16x8 ah[4], bh[4];
#pragma unroll
    for (int i = 0; i < 4; ++i) {
      ah[i] = *(const f16x8*)&As[cur][wr * 64 + i * 16 + nx][g * 8];
      bh[i] = *(const f16x8*)&Bs[cur][wc * 64 + i * 16 + nx][g * 8];
    }
#pragma unroll
    for (int i = 0; i < 4; ++i)
#pragma unroll
      for (int j = 0; j < 4; ++j)
        acc[i][j] = MFMA16(ah[i], bh[j], acc[i][j]);
    __builtin_amdgcn_s_barrier();
  }
#pragma unroll
  for (int j = 0; j < 4; ++j) {
    const int col = n0 + wc * 64 + j * 16 + nx;
    const float bz = bias[col];
#pragma unroll
    for (int i = 0; i < 4; ++i) {
      const int row0 = m0 + wr * 64 + i * 16 + g * 4;
#pragma unroll
      for (int r = 0; r < 4; ++r)
        Cout[(size_t)(row0 + r) * Dm + col] = acc[i][j][r] + bz;
    }
  }
}

// ---------------------------------------------------------------------------
// RMSNorm over full D + 3D rope; fp32 in -> fp16 rows in-place.
// Q pre-scaled by 1/sqrt(HD) * log2(e)  (softmax exp folded into exp2).
// ---------------------------------------------------------------------------
__global__ __launch_bounds__(256) void rmsnorm_rope_f16(
    float* __restrict__ q, float* __restrict__ k,
    const float* __restrict__ gq, const float* __restrict__ gk,
    const float* __restrict__ fcos, const float* __restrict__ fsin)
{
  const int l = blockIdx.x;
  const int tid = threadIdx.x;
  const int d0 = tid * 6;
  float qv[6], kv[6];
  float sq = 0.f, sk = 0.f;
  const float* qp = &q[(size_t)l * Dm + d0];
  const float* kp = &k[(size_t)l * Dm + d0];
#pragma unroll
  for (int i = 0; i < 6; i++) {
    qv[i] = qp[i]; sq += qv[i] * qv[i];
    kv[i] = kp[i]; sk += kv[i] * kv[i];
  }
#pragma unroll
  for (int s = 1; s < 64; s <<= 1) {
    sq += __shfl_xor(sq, s);
    sk += __shfl_xor(sk, s);
  }
  __shared__ float redq[4], redk[4];
  if ((tid & 63) == 0) { redq[tid >> 6] = sq; redk[tid >> 6] = sk; }
  __syncthreads();
  sq = redq[0] + redq[1] + redq[2] + redq[3];
  sk = redk[0] + redk[1] + redk[2] + redk[3];
  const float rq = rsqrtf(sq * (1.f / (float)Dm) + 1e-6f);
  const float rk = rsqrtf(sk * (1.f / (float)Dm) + 1e-6f);
  const float qscale = 0.08838834764831845f * LOG2E;   // 1/sqrt(128) * log2(e)
  const int f = l >> 10, h = (l >> 5) & 31, w = l & 31;
  unsigned short* qo = (unsigned short*)q + (size_t)l * Dm;
  unsigned short* ko = (unsigned short*)k + (size_t)l * Dm;
#pragma unroll
  for (int i = 0; i < 3; i++) {
    const int d = d0 + 2 * i;
    const int cc = (d & (HDm - 1)) >> 1;
    const int pos = (cc < S1c) ? f : ((cc < S1c + S2c) ? h : w);
    const float co = fcos[pos * 64 + cc];
    const float si = fsin[pos * 64 + cc];
    const float xr = qv[2 * i]     * rq * gq[d];
    const float xi = qv[2 * i + 1] * rq * gq[d + 1];
    *(unsigned int*)&qo[d] =
        pack_f16((xr * co - xi * si) * qscale, (xr * si + xi * co) * qscale);
    const float yr = kv[2 * i]     * rk * gk[d];
    const float yi = kv[2 * i + 1] * rk * gk[d + 1];
    *(unsigned int*)&ko[d] = pack_f16(yr * co - yi * si, yr * si + yi * co);
  }
}

// ---------------------------------------------------------------------------
// Flash attention, all-fp16 MFMA, fixed-max softmax, split-KV x2.
// (R2-verified version, 126.3 us.) Double-buffered K/V staging, ONE barrier
// per 32-kv tile. Q pre-scaled by log2e, S-acc init -MFIX*log2e -> bare
// v_exp_f32. l on the matrix pipe via all-ones B-fragment (9th acc tile).
// NEW (inert-safe): s_setprio(1) around the MFMA clusters (T5).
// ---------------------------------------------------------------------------
__global__ __launch_bounds__(256, 3) void attn_f16(
    const unsigned short* __restrict__ qs, const unsigned short* __restrict__ ks,
    const unsigned short* __restrict__ vT,
    float* __restrict__ Op0, float* __restrict__ Op1,
    float* __restrict__ stats)
{
  __shared__ __align__(16) unsigned short Ks[2][32][136];
  __shared__ __align__(16) unsigned short Vs[2][128][40];
  __shared__ __align__(16) unsigned short Ps[4][32][40];

  const int tid = threadIdx.x;
  const int w = tid >> 6, lane = tid & 63;
  const int nx = lane & 15, g = lane >> 4;
  const int head = blockIdx.y;
  const int half = blockIdx.z;
  const int qbase = blockIdx.x * 128 + w * 32;
  const int kvbase = half * (Ltok / 2);
  float* __restrict__ Op = half ? Op1 : Op0;

  const float NEGMFIX2 = -MFIX * LOG2E;   // -7.2134752

  // all-ones B fragment for the l-column MFMA (registers, no LDS)
  f16x8 vones;
#pragma unroll
  for (int i = 0; i < 8; i++) vones[i] = (_Float16)1.0f;

  // ---- Q fragments (pre-scaled fp16 rows of length Dm) ----
  f16x8 qf[2][4];
#pragma unroll
  for (int s = 0; s < 2; s++) {
    const unsigned short* qp =
        &qs[(size_t)(qbase + s * 16 + nx) * Dm + head * HDm + g * 8];
#pragma unroll
    for (int c = 0; c < 4; c++) qf[s][c] = *(const f16x8*)(qp + c * 32);
  }

  f32x4 oacc[2][9];
#pragma unroll
  for (int s = 0; s < 2; s++)
#pragma unroll
    for (int nt = 0; nt < 9; nt++) oacc[s][nt] = (f32x4){0.f, 0.f, 0.f, 0.f};

  const int krow = tid >> 3, kchb = (tid & 7) << 4;
  const int vrow = tid >> 1, vseg = (tid & 1) << 4;

  const unsigned short* kg = &ks[(size_t)(kvbase + krow) * Dm + head * HDm + kchb];
  const unsigned short* vg = &vT[((size_t)head * HDm + vrow) * Ltok + kvbase + vseg];

  // preload tile 0 into buffer 0
  {
    uint4 ka = *(const uint4*)kg, kb4 = *(const uint4*)(kg + 8);
    uint4 va = *(const uint4*)vg, vb4 = *(const uint4*)(vg + 8);
    *(uint4*)&Ks[0][krow][kchb]     = ka;
    *(uint4*)&Ks[0][krow][kchb + 8] = kb4;
    *(uint4*)&Vs[0][vrow][vseg]     = va;
    *(uint4*)&Vs[0][vrow][vseg + 8] = vb4;
  }
  __syncthreads();

  const int NIT = Ltok / 2 / 32;   // 64
  for (int t = 0; t < NIT; t++) {
    const int cur = t & 1, nxt = cur ^ 1;
    const bool pref = (t + 1 < NIT);
    uint4 ka, kb4, va, vb4;
    if (pref) {           // issue t+1 global loads early
      kg += 32 * Dm;
      vg += 32;
      ka  = *(const uint4*)kg;  kb4 = *(const uint4*)(kg + 8);
      va  = *(const uint4*)vg;  vb4 = *(const uint4*)(vg + 8);
    }

    // ---- S^T = K · Q^T  (C-in = -MFIX*log2e, so p = exp2(sa) directly) ----
    f32x4 sa[2][2];
#pragma unroll
    for (int s = 0; s < 2; s++)
#pragma unroll
      for (int mt = 0; mt < 2; mt++)
        sa[s][mt] = (f32x4){NEGMFIX2, NEGMFIX2, NEGMFIX2, NEGMFIX2};
    __builtin_amdgcn_s_setprio(1);
#pragma unroll
    for (int c = 0; c < 4; c++) {
      f16x8 k0f = *(const f16x8*)&Ks[cur][nx][c * 32 + g * 8];
      f16x8 k1f = *(const f16x8*)&Ks[cur][16 + nx][c * 32 + g * 8];
#pragma unroll
      for (int s = 0; s < 2; s++) {
        sa[s][0] = MFMA16(k0f, qf[s][c], sa[s][0]);
        sa[s][1] = MFMA16(k1f, qf[s][c], sa[s][1]);
      }
    }
    __builtin_amdgcn_s_setprio(0);

    // ---- softmax numerator: p = exp2(sa), bare v_exp_f32 ----
#pragma unroll
    for (int s = 0; s < 2; s++) {
      float p[8];
#pragma unroll
      for (int r = 0; r < 4; r++) {
        p[r]     = __builtin_amdgcn_exp2f(sa[s][0][r]);
        p[4 + r] = __builtin_amdgcn_exp2f(sa[s][1][r]);
      }
#pragma unroll
      for (int mt = 0; mt < 2; mt++) {
        unsigned int u0 = pack_f16(p[4 * mt + 0], p[4 * mt + 1]);
        unsigned int u1 = pack_f16(p[4 * mt + 2], p[4 * mt + 3]);
        *(uint2*)&Ps[w][s * 16 + nx][mt * 16 + g * 4] = make_uint2(u0, u1);
      }
    }
    __builtin_amdgcn_sched_barrier(0);  // Ps write -> read (same wave) ordering

    // ---- O += P · V   (tile 8 = ones-fragment -> l in every column) ----
    f16x8 ph[2];
#pragma unroll
    for (int s = 0; s < 2; s++)
      ph[s] = *(const f16x8*)&Ps[w][s * 16 + nx][g * 8];
    __builtin_amdgcn_s_setprio(1);
#pragma unroll
    for (int nt = 0; nt < 8; nt++) {
      f16x8 vh = *(const f16x8*)&Vs[cur][nt * 16 + nx][g * 8];
#pragma unroll
      for (int s = 0; s < 2; s++)
        oacc[s][nt] = MFMA16(ph[s], vh, oacc[s][nt]);
    }
#pragma unroll
    for (int s = 0; s < 2; s++)
      oacc[s][8] = MFMA16(ph[s], vones, oacc[s][8]);
    __builtin_amdgcn_s_setprio(0);

    if (pref) {           // stage t+1 into the other buffer
      *(uint4*)&Ks[nxt][krow][kchb]     = ka;
      *(uint4*)&Ks[nxt][krow][kchb + 8] = kb4;
      *(uint4*)&Vs[nxt][vrow][vseg]     = va;
      *(uint4*)&Vs[nxt][vrow][vseg + 8] = vb4;
    }
    __syncthreads();
  }

  // ---- epilogue: raw partial O + l stats (l = oacc[s][8], any column) ----
#pragma unroll
  for (int s = 0; s < 2; s++) {
#pragma unroll
    for (int nt = 0; nt < 8; nt++)
#pragma unroll
      for (int r = 0; r < 4; r++)
        Op[(size_t)(qbase + s * 16 + g * 4 + r) * Dm + head * HDm + nt * 16 + nx] =
            oacc[s][nt][r];
    if (nx == 0) {
#pragma unroll
      for (int r = 0; r < 4; r++)
        stats[((size_t)half * Ltok + qbase + s * 16 + g * 4 + r) * NHd + head] =
            oacc[s][8][r];
    }
  }
}

// ---------------------------------------------------------------------------
// Combine the two KV-half partials (same fixed M -> exact merge); emit fp16
// rows for the out-projection.
// ---------------------------------------------------------------------------
__global__ __launch_bounds__(384) void combine_f16(
    const float* __restrict__ Op0, const float* __restrict__ Op1,
    const float* __restrict__ stats, unsigned short* __restrict__ oh)
{
  const int row = blockIdx.x;
  const int c4 = threadIdx.x * 4;
  const int head = c4 >> 7;
  const float l0 = stats[(size_t)row * NHd + head];
  const float l1 = stats[((size_t)Ltok + row) * NHd + head];
  const float rl = 1.f / (l0 + l1);
  float4 o0 = *(const float4*)&Op0[(size_t)row * Dm + c4];
  float4 o1 = *(const float4*)&Op1[(size_t)row * Dm + c4];
  uint2 p;
  p.x = pack_f16((o0.x + o1.x) * rl, (o0.y + o1.y) * rl);
  p.y = pack_f16((o0.z + o1.z) * rl, (o0.w + o1.w) * rl);
  *(uint2*)&oh[(size_t)row * Dm + c4] = p;
}

// ---------------------------------------------------------------------------
extern "C" void kernel_launch(void* const* d_in, const int* in_sizes, int n_in,
                              void* d_out, int out_size, void* d_ws, size_t ws_size,
                              hipStream_t stream)
{
  const float* x    = (const float*)d_in[0];
  const float* wq   = (const float*)d_in[1];
  const float* wk   = (const float*)d_in[2];
  const float* wv   = (const float*)d_in[3];
  const float* wo   = (const float*)d_in[4];
  const float* bq   = (const float*)d_in[5];
  const float* bk   = (const float*)d_in[6];
  const float* bv   = (const float*)d_in[7];
  const float* bo   = (const float*)d_in[8];
  const float* gq   = (const float*)d_in[9];
  const float* gk   = (const float*)d_in[10];
  const float* fcos = (const float*)d_in[11];
  const float* fsin = (const float*)d_in[12];
  float* out = (float*)d_out;

  const size_t LD = (size_t)Ltok * Dm;       // 6.29 M elems
  const size_t WH = (size_t)Dm * Dm;         // 2.36 M shorts per fp16 weight
  float* base = (float*)d_ws;
  // Lifetime-checked layout (float offsets, total 5.27*LD = 132.6 MB):
  //  [0,   LD)      qb fp32 -> fp16 rows in place; after attn: oh fp16 rows
  //  [LD, 2LD)      kb fp32 -> fp16 rows in place
  //  [2LD, 2.5LD)   vT fp16 V^T (written by gemm_qkv, read by attn)
  //  [2.5LD, 3.5LD) Op0 fp32 (attn out); xh fp16 aliases [2.5LD,3LD) before
  //  [3.5LD, 4.5LD) Op1 fp32
  //  [4.5LD, 5.25LD) wqh|wkh|wvh|woh fp16 weights
  //  [5.25LD, ...)  stats (2*4096*12 fp32)
  float* qb = base;
  float* kb = base + LD;
  unsigned short* vT  = (unsigned short*)(base + 2 * LD);
  unsigned short* xh  = (unsigned short*)(base + 2 * LD + LD / 2);
  float* Op0 = base + 2 * LD + LD / 2;
  float* Op1 = Op0 + LD;
  unsigned short* wqh = (unsigned short*)(Op1 + LD);
  unsigned short* woh = wqh + 3 * WH;
  unsigned short* oh  = (unsigned short*)base;   // over dead q fp16 rows
  float* stats = (float*)(wqh + 4 * WH);

  const int xslots = (int)(LD / 4);          // 1572864
  const int w4     = (int)(WH / 4);          // 589824 = 2304*256
  dim3 gqkv(3 * Dm / 128, Ltok / 128);       // (36, 32)
  dim3 gout(Dm / 128, Ltok / 128);           // (12, 32)

  cvt_f16<<<(xslots + 255) / 256, 256, 0, stream>>>(x, xh, xslots);
  cvt_w4_f16<<<dim3(w4 / 256, 4), 256, 0, stream>>>(wq, wk, wv, wo, wqh);

  gemm_qkv_f16<<<gqkv, 256, 0, stream>>>(xh, wqh, bq, bk, bv, qb, kb, vT);
  rmsnorm_rope_f16<<<Ltok, 256, 0, stream>>>(qb, kb, gq, gk, fcos, fsin);
  attn_f16<<<dim3(Ltok / 128, NHd, 2), 256, 0, stream>>>(
      (const unsigned short*)qb, (const unsigned short*)kb, vT, Op0, Op1, stats);
  combine_f16<<<Ltok, 384, 0, stream>>>(Op0, Op1, stats, oh);
  gemm_nt_f16<<<gout, 256, 0, stream>>>(oh, woh, bo, out);
}